// Round 3
// baseline (1501.997 us; speedup 1.0000x reference)
//
#include <hip/hip_runtime.h>
#include <math.h>

#define NROWS 65536
#define D 256
#define K 1024

// d_out offsets (floats)
#define OFF_Q     0
#define OFF_LOSS  16777216
#define OFF_IDX   16777217
#define OFF_CS    16842753
#define OFF_EMAW  16843777
#define OFF_UPD   17105921

// ws offsets (bytes)
#define WS_DW       0           // 262144 f32
#define WS_COUNTS   1048576     // 1024 f32
#define WS_ZERO     1052672     // zero range [0, WS_ZERO)
#define WS_IDX      1052672     // 65536 int
#define WS_SQX      1314816     // 65536 f32
#define WS_SQE      1576960     // 1024 f32
#define WS_LOSSP    1581056     // 2048 double
#define WS_CVAL     1597440     // 4*65536 f32
#define WS_CIDX     2646016     // 4*65536 int  (ends 3694592)

// ---------------- K0: row sum-of-squares, numpy AVX512 pairwise order ----------------
__global__ __launch_bounds__(256) void k_sq(const float* __restrict__ a_,
                                            float* __restrict__ dst, int n)
{
#pragma clang fp contract(off)
    int r = blockIdx.x * 256 + threadIdx.x;
    if (r >= n) return;
    const float* a = a_ + (size_t)r * 256;
    float h[2];
#pragma unroll
    for (int hh = 0; hh < 2; ++hh) {
        const int b = hh * 128;
        float V[16];
#pragma unroll
        for (int l = 0; l < 16; ++l) {
            float q0 = a[b+l]      * a[b+l];
            float q1 = a[b+16+l]   * a[b+16+l];
            float q2 = a[b+32+l]   * a[b+32+l];
            float q3 = a[b+48+l]   * a[b+48+l];
            float q4 = a[b+64+l]   * a[b+64+l];
            float q5 = a[b+80+l]   * a[b+80+l];
            float q6 = a[b+96+l]   * a[b+96+l];
            float q7 = a[b+112+l]  * a[b+112+l];
            V[l] = ((q0 + q1) + (q2 + q3)) + ((q4 + q5) + (q6 + q7));
        }
        float t[8];
#pragma unroll
        for (int l = 0; l < 8; ++l) t[l] = V[l] + V[l+8];
        float u[4];
#pragma unroll
        for (int l = 0; l < 4; ++l) u[l] = t[l] + t[l+4];
        h[hh] = (u[0] + u[2]) + (u[1] + u[3]);
    }
    dst[r] = h[0] + h[1];
}

// ---------------- K1: distances with BLAS-order f32 dots + per-lane argmin ----------------
// wave <-> (row-group of 64, quarter of codebook); lane <-> row
__global__ __launch_bounds__(256) void k_dist(
    const float* __restrict__ x, const float* __restrict__ ew,
    const float* __restrict__ sqx, const float* __restrict__ sqe,
    float* __restrict__ cval, int* __restrict__ cidx)
{
#pragma clang fp contract(off)
    const int lane = threadIdx.x & 63;
    const int q = __builtin_amdgcn_readfirstlane(threadIdx.x >> 6);
    const int r = blockIdx.x * 64 + lane;
    const float4* __restrict__ X4 = (const float4*)x;
    const float4* __restrict__ E4 = (const float4*)ew;
    const float sxr = sqx[r];
    float best = 3.4e38f;
    int bestc = 0;
    const int qbase = q * 256;
#pragma unroll 1
    for (int pass = 0; pass < 4; ++pass) {
        const int c0 = qbase + pass * 64;
        float acc[64];
#pragma unroll
        for (int j = 0; j < 64; ++j) acc[j] = 0.f;
#pragma unroll 1
        for (int kc = 0; kc < 32; ++kc) {
            float4 xa = X4[(size_t)r * 64 + kc * 2];
            float4 xb = X4[(size_t)r * 64 + kc * 2 + 1];
            float xk[8] = {xa.x, xa.y, xa.z, xa.w, xb.x, xb.y, xb.z, xb.w};
#pragma unroll
            for (int j8 = 0; j8 < 8; ++j8) {
                float ee[8][8];
#pragma unroll
                for (int jj = 0; jj < 8; ++jj) {
                    int ci = __builtin_amdgcn_readfirstlane(c0 + j8 * 8 + jj);
                    float4 ea = E4[(size_t)ci * 64 + kc * 2];
                    float4 eb = E4[(size_t)ci * 64 + kc * 2 + 1];
                    ee[jj][0] = ea.x; ee[jj][1] = ea.y; ee[jj][2] = ea.z; ee[jj][3] = ea.w;
                    ee[jj][4] = eb.x; ee[jj][5] = eb.y; ee[jj][6] = eb.z; ee[jj][7] = eb.w;
                }
                // k ascending (kc outer, k inner) => exact BLAS sequential-k FMA order
#pragma unroll
                for (int k = 0; k < 8; ++k)
#pragma unroll
                    for (int jj = 0; jj < 8; ++jj)
                        acc[j8*8+jj] = __builtin_fmaf(xk[k], ee[jj][k], acc[j8*8+jj]);
            }
        }
        // epilogue: dist = (sqx - 2*dot) + sqe, two separate f32 roundings, scan c ascending
#pragma unroll
        for (int j = 0; j < 64; ++j) {
            const int c = c0 + j;
            float t = sxr - 2.0f * acc[j];
            float d = t + sqe[__builtin_amdgcn_readfirstlane(c)];
            if (d < best) { best = d; bestc = c; }
        }
    }
    cval[q * 65536 + r] = best;
    cidx[q * 65536 + r] = bestc;
}

// ---------------- K1b: merge the 4 quarter-candidates per row ----------------
__global__ __launch_bounds__(256) void k_merge(
    const float* __restrict__ cval, const int* __restrict__ cidx,
    int* __restrict__ idxi, float* __restrict__ idxf)
{
    int r = blockIdx.x * 256 + threadIdx.x;
    float best = 3.4e38f; int bi = 0x7fffffff;
#pragma unroll
    for (int q = 0; q < 4; ++q) {
        float v = cval[q * 65536 + r];
        int c = cidx[q * 65536 + r];
        if (v < best || (v == best && c < bi)) { best = v; bi = c; }
    }
    idxi[r] = bi;
    idxf[r] = (float)bi;
}

// ---------------- K2: gather/quantize + loss partials + scatter counts/dw ----------------
__global__ __launch_bounds__(256) void k_scatter(
    const float* __restrict__ x, const float* __restrict__ ew,
    const int* __restrict__ idx_in,
    float* __restrict__ q_out, float* __restrict__ counts,
    float* __restrict__ dw, double* __restrict__ lossp)
{
    const int tid = threadIdx.x;
    const int lane = tid & 63, wid = tid >> 6;
    __shared__ float wsum[4];
    float lsum = 0.f;
    const int rowbase = blockIdx.x * 32;
    for (int rr = 0; rr < 8; ++rr) {
        int row = rowbase + wid * 8 + rr;
        int idx = idx_in[row];
        const float4 e  = *(const float4*)&ew[(size_t)idx * D + lane * 4];
        const float4 xv = *(const float4*)&x[(size_t)row * D + lane * 4];
        *(float4*)&q_out[(size_t)row * D + lane * 4] = e;
        float dx = e.x - xv.x, dy = e.y - xv.y, dz = e.z - xv.z, dv = e.w - xv.w;
        lsum += dx * dx + dy * dy + dz * dz + dv * dv;
        atomicAdd(&dw[(size_t)idx * D + lane * 4 + 0], xv.x);
        atomicAdd(&dw[(size_t)idx * D + lane * 4 + 1], xv.y);
        atomicAdd(&dw[(size_t)idx * D + lane * 4 + 2], xv.z);
        atomicAdd(&dw[(size_t)idx * D + lane * 4 + 3], xv.w);
        if (lane == 0) atomicAdd(&counts[idx], 1.0f);
    }
#pragma unroll
    for (int m = 1; m < 64; m <<= 1) lsum += __shfl_xor(lsum, m);
    if (lane == 0) wsum[wid] = lsum;
    __syncthreads();
    if (tid == 0) lossp[blockIdx.x] = (double)wsum[0] + wsum[1] + wsum[2] + wsum[3];
}

// ---------------- K3: finalize new_cs (+ n) and loss ----------------
__global__ __launch_bounds__(1024) void k_finalize(
    const float* __restrict__ ema_cs, const float* __restrict__ counts,
    const double* __restrict__ lossp, float* __restrict__ out)
{
    __shared__ double red[1024];
    const int tid = threadIdx.x;
    float raw = ema_cs[tid] * 0.99f + 0.01f * counts[tid];
    red[tid] = (double)raw;
    __syncthreads();
    for (int s = 512; s > 0; s >>= 1) {
        if (tid < s) red[tid] += red[tid + s];
        __syncthreads();
    }
    double n = red[0];
    __syncthreads();
    float csn = (raw + 1e-5f) * (float)(n / (n + 1024.0 * 1e-5));
    out[OFF_CS + tid] = csn;
    red[tid] = lossp[tid] + lossp[tid + 1024];
    __syncthreads();
    for (int s = 512; s > 0; s >>= 1) {
        if (tid < s) red[tid] += red[tid + s];
        __syncthreads();
    }
    if (tid == 0) out[OFF_LOSS] = (float)(red[0] * 1.25 / 16777216.0);
}

// ---------------- K4: new_ema_w + updated_embed ----------------
__global__ __launch_bounds__(256) void k_ema(
    const float* __restrict__ ema_w, const float* __restrict__ dw,
    const float* __restrict__ cs_out, float* __restrict__ out)
{
    int id = blockIdx.x * 256 + threadIdx.x;   // 0..262143
    int k = id >> 8;
    float nw = ema_w[id] * 0.99f + 0.01f * dw[id];
    out[OFF_EMAW + id] = nw;
    out[OFF_UPD + id] = nw / cs_out[k];
}

extern "C" void kernel_launch(void* const* d_in, const int* in_sizes, int n_in,
                              void* d_out, int out_size, void* d_ws, size_t ws_size,
                              hipStream_t stream)
{
    const float* x      = (const float*)d_in[0];
    const float* ew     = (const float*)d_in[1];
    const float* ema_cs = (const float*)d_in[2];
    const float* ema_w  = (const float*)d_in[3];
    float* out = (float*)d_out;
    char* ws = (char*)d_ws;

    float*  dw      = (float*)(ws + WS_DW);
    float*  counts  = (float*)(ws + WS_COUNTS);
    int*    idxi    = (int*)(ws + WS_IDX);
    float*  sqx     = (float*)(ws + WS_SQX);
    float*  sqe     = (float*)(ws + WS_SQE);
    double* lossp   = (double*)(ws + WS_LOSSP);
    float*  cval    = (float*)(ws + WS_CVAL);
    int*    cidx    = (int*)(ws + WS_CIDX);

    hipMemsetAsync(ws, 0, WS_ZERO, stream);
    hipLaunchKernelGGL(k_sq, dim3(NROWS / 256), dim3(256), 0, stream, x, sqx, NROWS);
    hipLaunchKernelGGL(k_sq, dim3(K / 256), dim3(256), 0, stream, ew, sqe, K);
    hipLaunchKernelGGL(k_dist, dim3(NROWS / 64), dim3(256), 0, stream,
                       x, ew, sqx, sqe, cval, cidx);
    hipLaunchKernelGGL(k_merge, dim3(NROWS / 256), dim3(256), 0, stream,
                       cval, cidx, idxi, out + OFF_IDX);
    hipLaunchKernelGGL(k_scatter, dim3(NROWS / 32), dim3(256), 0, stream,
                       x, ew, idxi, out + OFF_Q, counts, dw, lossp);
    hipLaunchKernelGGL(k_finalize, dim3(1), dim3(1024), 0, stream,
                       ema_cs, counts, lossp, out);
    hipLaunchKernelGGL(k_ema, dim3(1024), dim3(256), 0, stream,
                       ema_w, dw, out + OFF_CS, out);
}

// Round 4
// 824.835 us; speedup vs baseline: 1.8210x; 1.8210x over previous
//
#include <hip/hip_runtime.h>
#include <math.h>

#define NROWS 65536
#define D 256
#define K 1024

// d_out offsets (floats)
#define OFF_Q     0
#define OFF_LOSS  16777216
#define OFF_IDX   16777217
#define OFF_CS    16842753
#define OFF_EMAW  16843777
#define OFF_UPD   17105921

// ws offsets (bytes)
#define WS_DW       0           // 262144 f32
#define WS_COUNTS   1048576     // 1024 f32
#define WS_ZERO     1052672     // zero range [0, WS_ZERO)
#define WS_IDX      1052672     // 65536 int
#define WS_SQX      1314816     // 65536 f32
#define WS_SQE      1576960     // 1024 f32
#define WS_LOSSP    1581056     // 2048 double

// ---------------- K0: row sum-of-squares, numpy AVX512 pairwise order ----------------
__global__ __launch_bounds__(256) void k_sq(const float* __restrict__ a_,
                                            float* __restrict__ dst, int n)
{
#pragma clang fp contract(off)
    int r = blockIdx.x * 256 + threadIdx.x;
    if (r >= n) return;
    const float* a = a_ + (size_t)r * 256;
    float h[2];
#pragma unroll
    for (int hh = 0; hh < 2; ++hh) {
        const int b = hh * 128;
        float V[16];
#pragma unroll
        for (int l = 0; l < 16; ++l) {
            float q0 = a[b+l]      * a[b+l];
            float q1 = a[b+16+l]   * a[b+16+l];
            float q2 = a[b+32+l]   * a[b+32+l];
            float q3 = a[b+48+l]   * a[b+48+l];
            float q4 = a[b+64+l]   * a[b+64+l];
            float q5 = a[b+80+l]   * a[b+80+l];
            float q6 = a[b+96+l]   * a[b+96+l];
            float q7 = a[b+112+l]  * a[b+112+l];
            V[l] = ((q0 + q1) + (q2 + q3)) + ((q4 + q5) + (q6 + q7));
        }
        float t[8];
#pragma unroll
        for (int l = 0; l < 8; ++l) t[l] = V[l] + V[l+8];
        float u[4];
#pragma unroll
        for (int l = 0; l < 4; ++l) u[l] = t[l] + t[l+4];
        h[hh] = (u[0] + u[2]) + (u[1] + u[3]);
    }
    dst[r] = h[0] + h[1];
}

// ---------------- K1: tiled f32 GEMM-argmin, numpy/BLAS-exact arithmetic ----------------
// 64 rows x 64 codes per tile, block = 256 threads (16x16 thread grid of 4x4)
// Per (row,code): single f32 accumulator, fmaf over k=0..255 ascending (BLAS order).
// dist = (sqx - 2*dot) + sqe  with two separate f32 roundings (numpy order).
// argmin: first-min over c ascending (ct asc, j asc, index-min tie-break in reduce).
__global__ __launch_bounds__(256) void k_argmin(
    const float* __restrict__ x, const float* __restrict__ ew,
    const float* __restrict__ sqx, const float* __restrict__ sqe,
    int* __restrict__ idx_out, float* __restrict__ idxf_out)
{
#pragma clang fp contract(off)
    __shared__ float xs[32][68];   // [d][row], 68 floats => 272B rows, 16B-aligned float4
    __shared__ float es[32][68];   // [d][code]
    const int tid = threadIdx.x;
    const int tx = tid & 15, ty = tid >> 4;
    const int row0 = blockIdx.x * 64;
    const int ld = tid & 31;       // d within chunk
    const int lr = tid >> 5;       // 0..7

    float best1[4];
    int bidx[4];
#pragma unroll
    for (int i = 0; i < 4; ++i) { best1[i] = 3.4e38f; bidx[i] = 0; }

    const float sx0 = sqx[row0 + ty * 4 + 0];
    const float sx1 = sqx[row0 + ty * 4 + 1];
    const float sx2 = sqx[row0 + ty * 4 + 2];
    const float sx3 = sqx[row0 + ty * 4 + 3];
    const float sxv[4] = {sx0, sx1, sx2, sx3};

    for (int ct = 0; ct < 16; ++ct) {
        float acc[4][4];
#pragma unroll
        for (int i = 0; i < 4; ++i)
#pragma unroll
            for (int j = 0; j < 4; ++j) acc[i][j] = 0.f;

        for (int dc = 0; dc < 8; ++dc) {
            __syncthreads();
#pragma unroll
            for (int p = 0; p < 8; ++p) {
                int r = lr + 8 * p;
                xs[ld][r] = x[(size_t)(row0 + r) * D + dc * 32 + ld];
                es[ld][r] = ew[(size_t)(ct * 64 + r) * D + dc * 32 + ld];
            }
            __syncthreads();
#pragma unroll
            for (int d = 0; d < 32; ++d) {
                float4 xv = *(const float4*)&xs[d][ty * 4];
                float4 ev = *(const float4*)&es[d][tx * 4];
                float xa[4] = {xv.x, xv.y, xv.z, xv.w};
                float ea[4] = {ev.x, ev.y, ev.z, ev.w};
#pragma unroll
                for (int i = 0; i < 4; ++i)
#pragma unroll
                    for (int j = 0; j < 4; ++j)
                        acc[i][j] = __builtin_fmaf(xa[i], ea[j], acc[i][j]);
            }
        }
        const int cbase = ct * 64 + tx * 4;
        const float se0 = sqe[cbase + 0];
        const float se1 = sqe[cbase + 1];
        const float se2 = sqe[cbase + 2];
        const float se3 = sqe[cbase + 3];
        const float sev[4] = {se0, se1, se2, se3};
#pragma unroll
        for (int i = 0; i < 4; ++i) {
            float v1 = 3.4e38f; int i1 = 0x7fffffff;
#pragma unroll
            for (int j = 0; j < 4; ++j) {
                float t = sxv[i] - 2.0f * acc[i][j];   // 2*acc exact; one rounding
                float s = t + sev[j];                  // second rounding (numpy order)
                if (s < v1) { v1 = s; i1 = cbase + j; } // j asc -> first-min
            }
            // butterfly reduce across the 16 lanes sharing this row group
#pragma unroll
            for (int m = 1; m < 16; m <<= 1) {
                float o1 = __shfl_xor(v1, m);
                int    oi = __shfl_xor(i1, m);
                if (o1 < v1 || (o1 == v1 && oi < i1)) { v1 = o1; i1 = oi; }
            }
            if (v1 < best1[i] || (v1 == best1[i] && i1 < bidx[i])) {
                best1[i] = v1; bidx[i] = i1;   // ct asc -> earlier code wins ties
            }
        }
    }
    if (tx == 0) {
#pragma unroll
        for (int i = 0; i < 4; ++i) {
            int row = row0 + ty * 4 + i;
            idx_out[row] = bidx[i];
            idxf_out[row] = (float)bidx[i];
        }
    }
}

// ---------------- K2: gather/quantize + loss partials + scatter counts/dw ----------------
__global__ __launch_bounds__(256) void k_scatter(
    const float* __restrict__ x, const float* __restrict__ ew,
    const int* __restrict__ idx_in,
    float* __restrict__ q_out, float* __restrict__ counts,
    float* __restrict__ dw, double* __restrict__ lossp)
{
    const int tid = threadIdx.x;
    const int lane = tid & 63, wid = tid >> 6;
    __shared__ float wsum[4];
    float lsum = 0.f;
    const int rowbase = blockIdx.x * 32;
    for (int rr = 0; rr < 8; ++rr) {
        int row = rowbase + wid * 8 + rr;
        int idx = idx_in[row];
        const float4 e  = *(const float4*)&ew[(size_t)idx * D + lane * 4];
        const float4 xv = *(const float4*)&x[(size_t)row * D + lane * 4];
        *(float4*)&q_out[(size_t)row * D + lane * 4] = e;
        float dx = e.x - xv.x, dy = e.y - xv.y, dz = e.z - xv.z, dv = e.w - xv.w;
        lsum += dx * dx + dy * dy + dz * dz + dv * dv;
        atomicAdd(&dw[(size_t)idx * D + lane * 4 + 0], xv.x);
        atomicAdd(&dw[(size_t)idx * D + lane * 4 + 1], xv.y);
        atomicAdd(&dw[(size_t)idx * D + lane * 4 + 2], xv.z);
        atomicAdd(&dw[(size_t)idx * D + lane * 4 + 3], xv.w);
        if (lane == 0) atomicAdd(&counts[idx], 1.0f);
    }
#pragma unroll
    for (int m = 1; m < 64; m <<= 1) lsum += __shfl_xor(lsum, m);
    if (lane == 0) wsum[wid] = lsum;
    __syncthreads();
    if (tid == 0) lossp[blockIdx.x] = (double)wsum[0] + wsum[1] + wsum[2] + wsum[3];
}

// ---------------- K3: finalize new_cs (+ n) and loss ----------------
__global__ __launch_bounds__(1024) void k_finalize(
    const float* __restrict__ ema_cs, const float* __restrict__ counts,
    const double* __restrict__ lossp, float* __restrict__ out)
{
    __shared__ double red[1024];
    const int tid = threadIdx.x;
    float raw = ema_cs[tid] * 0.99f + 0.01f * counts[tid];
    red[tid] = (double)raw;
    __syncthreads();
    for (int s = 512; s > 0; s >>= 1) {
        if (tid < s) red[tid] += red[tid + s];
        __syncthreads();
    }
    double n = red[0];
    __syncthreads();
    float csn = (raw + 1e-5f) * (float)(n / (n + 1024.0 * 1e-5));
    out[OFF_CS + tid] = csn;
    red[tid] = lossp[tid] + lossp[tid + 1024];
    __syncthreads();
    for (int s = 512; s > 0; s >>= 1) {
        if (tid < s) red[tid] += red[tid + s];
        __syncthreads();
    }
    if (tid == 0) out[OFF_LOSS] = (float)(red[0] * 1.25 / 16777216.0);
}

// ---------------- K4: new_ema_w + updated_embed ----------------
__global__ __launch_bounds__(256) void k_ema(
    const float* __restrict__ ema_w, const float* __restrict__ dw,
    const float* __restrict__ cs_out, float* __restrict__ out)
{
    int id = blockIdx.x * 256 + threadIdx.x;   // 0..262143
    int k = id >> 8;
    float nw = ema_w[id] * 0.99f + 0.01f * dw[id];
    out[OFF_EMAW + id] = nw;
    out[OFF_UPD + id] = nw / cs_out[k];
}

extern "C" void kernel_launch(void* const* d_in, const int* in_sizes, int n_in,
                              void* d_out, int out_size, void* d_ws, size_t ws_size,
                              hipStream_t stream)
{
    const float* x      = (const float*)d_in[0];
    const float* ew     = (const float*)d_in[1];
    const float* ema_cs = (const float*)d_in[2];
    const float* ema_w  = (const float*)d_in[3];
    float* out = (float*)d_out;
    char* ws = (char*)d_ws;

    float*  dw      = (float*)(ws + WS_DW);
    float*  counts  = (float*)(ws + WS_COUNTS);
    int*    idxi    = (int*)(ws + WS_IDX);
    float*  sqx     = (float*)(ws + WS_SQX);
    float*  sqe     = (float*)(ws + WS_SQE);
    double* lossp   = (double*)(ws + WS_LOSSP);

    hipMemsetAsync(ws, 0, WS_ZERO, stream);
    hipLaunchKernelGGL(k_sq, dim3(NROWS / 256), dim3(256), 0, stream, x, sqx, NROWS);
    hipLaunchKernelGGL(k_sq, dim3(K / 256), dim3(256), 0, stream, ew, sqe, K);
    hipLaunchKernelGGL(k_argmin, dim3(NROWS / 64), dim3(256), 0, stream,
                       x, ew, sqx, sqe, idxi, out + OFF_IDX);
    hipLaunchKernelGGL(k_scatter, dim3(NROWS / 32), dim3(256), 0, stream,
                       x, ew, idxi, out + OFF_Q, counts, dw, lossp);
    hipLaunchKernelGGL(k_finalize, dim3(1), dim3(1024), 0, stream,
                       ema_cs, counts, lossp, out);
    hipLaunchKernelGGL(k_ema, dim3(1024), dim3(256), 0, stream,
                       ema_w, dw, out + OFF_CS, out);
}

// Round 5
// 606.718 us; speedup vs baseline: 2.4756x; 1.3595x over previous
//
#include <hip/hip_runtime.h>
#include <math.h>

#define NROWS 65536
#define D 256
#define K 1024

// d_out offsets (floats)
#define OFF_Q     0
#define OFF_LOSS  16777216
#define OFF_IDX   16777217
#define OFF_CS    16842753
#define OFF_EMAW  16843777
#define OFF_UPD   17105921

// ws offsets (bytes)
#define WS_HIST     0          // 1024 int  (memset)
#define WS_OFFS     4096       // 1024 int
#define WS_CURS     8192       // 1024 int
#define WS_IDX      12288      // 65536 int
#define WS_ROWIDS   274432     // 65536 int
#define WS_SQX      536576     // 65536 f32
#define WS_SQE      798720     // 1024 f32
#define WS_DW       802816     // 262144 f32
#define WS_LOSSP    1851392    // 1024 double (ends 1859584)

// ---------------- K0: row sum-of-squares, numpy AVX512 pairwise order ----------------
__global__ __launch_bounds__(256) void k_sq(const float* __restrict__ a_,
                                            float* __restrict__ dst, int n)
{
#pragma clang fp contract(off)
    int r = blockIdx.x * 256 + threadIdx.x;
    if (r >= n) return;
    const float* a = a_ + (size_t)r * 256;
    float h[2];
#pragma unroll
    for (int hh = 0; hh < 2; ++hh) {
        const int b = hh * 128;
        float V[16];
#pragma unroll
        for (int l = 0; l < 16; ++l) {
            float q0 = a[b+l]      * a[b+l];
            float q1 = a[b+16+l]   * a[b+16+l];
            float q2 = a[b+32+l]   * a[b+32+l];
            float q3 = a[b+48+l]   * a[b+48+l];
            float q4 = a[b+64+l]   * a[b+64+l];
            float q5 = a[b+80+l]   * a[b+80+l];
            float q6 = a[b+96+l]   * a[b+96+l];
            float q7 = a[b+112+l]  * a[b+112+l];
            V[l] = ((q0 + q1) + (q2 + q3)) + ((q4 + q5) + (q6 + q7));
        }
        float t[8];
#pragma unroll
        for (int l = 0; l < 8; ++l) t[l] = V[l] + V[l+8];
        float u[4];
#pragma unroll
        for (int l = 0; l < 4; ++l) u[l] = t[l] + t[l+4];
        h[hh] = (u[0] + u[2]) + (u[1] + u[3]);
    }
    dst[r] = h[0] + h[1];
}

// ---------------- K1: tiled f32 GEMM-argmin, numpy/BLAS-exact arithmetic ----------------
// 64 rows/block; 4 ct-tiles of 256 codes; per-thread acc[4][16].
// Per (row,code): single f32 accumulator, fmaf over k=0..255 ascending (BLAS order).
// dist = (sqx - 2*dot) + sqe  with two separate f32 roundings (numpy order).
// argmin: lex-min (value, index) == np.argmin first-min.
__global__ __launch_bounds__(256, 3) void k_argmin(
    const float* __restrict__ x, const float* __restrict__ ew,
    const float* __restrict__ sqx, const float* __restrict__ sqe,
    int* __restrict__ idx_out, float* __restrict__ idxf_out,
    int* __restrict__ hist)
{
#pragma clang fp contract(off)
    __shared__ float xs[32][68];    // [d][row]   8704 B
    __shared__ float es[32][260];   // [d][code] 33280 B
    const int tid = threadIdx.x;
    const int tx = tid & 15, ty = tid >> 4;
    const int row0 = blockIdx.x * 64;
    const float4* __restrict__ X4 = (const float4*)x;
    const float4* __restrict__ E4 = (const float4*)ew;

    float best1[4];
    int bidx[4];
#pragma unroll
    for (int i = 0; i < 4; ++i) { best1[i] = 3.4e38f; bidx[i] = 0; }

    const float4 sx4 = *(const float4*)&sqx[row0 + ty * 4];
    const float sxv[4] = {sx4.x, sx4.y, sx4.z, sx4.w};

    for (int ct = 0; ct < 4; ++ct) {
        float acc[4][16];
#pragma unroll
        for (int i = 0; i < 4; ++i)
#pragma unroll
            for (int j = 0; j < 16; ++j) acc[i][j] = 0.f;

        for (int dc = 0; dc < 8; ++dc) {
            __syncthreads();
            // stage x tile: 64 rows x 32 d (2 rounds of 8-row x 32-d per wave-grp)
#pragma unroll
            for (int q = 0; q < 2; ++q) {
                const int row = (tid >> 3) + 32 * q;
                const int db = 4 * (tid & 7);
                float4 v = X4[(size_t)(row0 + row) * 64 + dc * 8 + (tid & 7)];
                xs[db + 0][row] = v.x;
                xs[db + 1][row] = v.y;
                xs[db + 2][row] = v.z;
                xs[db + 3][row] = v.w;
            }
            // stage e tile: 256 codes x 32 d (8 rounds)
#pragma unroll
            for (int q = 0; q < 8; ++q) {
                const int c = (tid >> 3) + 32 * q;
                const int db = 4 * (tid & 7);
                float4 v = E4[(size_t)(ct * 256 + c) * 64 + dc * 8 + (tid & 7)];
                es[db + 0][c] = v.x;
                es[db + 1][c] = v.y;
                es[db + 2][c] = v.z;
                es[db + 3][c] = v.w;
            }
            __syncthreads();
#pragma unroll
            for (int d = 0; d < 32; ++d) {
                const float4 xv = *(const float4*)&xs[d][ty * 4];
                const float xa[4] = {xv.x, xv.y, xv.z, xv.w};
#pragma unroll
                for (int p = 0; p < 4; ++p) {
                    const float4 ev = *(const float4*)&es[d][p * 64 + tx * 4];
                    const float ea[4] = {ev.x, ev.y, ev.z, ev.w};
#pragma unroll
                    for (int i = 0; i < 4; ++i)
#pragma unroll
                        for (int j = 0; j < 4; ++j)
                            acc[i][p * 4 + j] =
                                __builtin_fmaf(xa[i], ea[j], acc[i][p * 4 + j]);
                }
            }
        }
        // epilogue for this ct: distances + per-thread first-min
        float sev[16];
#pragma unroll
        for (int p = 0; p < 4; ++p) {
            const float4 se4 = *(const float4*)&sqe[ct * 256 + p * 64 + tx * 4];
            sev[p * 4 + 0] = se4.x; sev[p * 4 + 1] = se4.y;
            sev[p * 4 + 2] = se4.z; sev[p * 4 + 3] = se4.w;
        }
#pragma unroll
        for (int i = 0; i < 4; ++i) {
            float v1 = 3.4e38f; int i1 = 0x7fffffff;
#pragma unroll
            for (int p = 0; p < 4; ++p)
#pragma unroll
                for (int j = 0; j < 4; ++j) {
                    float t = sxv[i] - 2.0f * acc[i][p * 4 + j]; // one rounding
                    float s = t + sev[p * 4 + j];                // second rounding
                    int c = ct * 256 + p * 64 + tx * 4 + j;      // ascending in (p,j)
                    if (s < v1 || (s == v1 && c < i1)) { v1 = s; i1 = c; }
                }
            // reduce across the 16 tx lanes (lex-min value,index)
#pragma unroll
            for (int m = 1; m < 16; m <<= 1) {
                float o1 = __shfl_xor(v1, m);
                int    oi = __shfl_xor(i1, m);
                if (o1 < v1 || (o1 == v1 && oi < i1)) { v1 = o1; i1 = oi; }
            }
            if (v1 < best1[i] || (v1 == best1[i] && i1 < bidx[i])) {
                best1[i] = v1; bidx[i] = i1;
            }
        }
    }
    if (tx == 0) {
#pragma unroll
        for (int i = 0; i < 4; ++i) {
            int row = row0 + ty * 4 + i;
            idx_out[row] = bidx[i];
            idxf_out[row] = (float)bidx[i];
            atomicAdd(&hist[bidx[i]], 1);
        }
    }
}

// ---------------- K2: prefix sum of histogram -> offsets + cursors ----------------
__global__ __launch_bounds__(1024) void k_prefix(
    const int* __restrict__ hist, int* __restrict__ offs, int* __restrict__ curs)
{
    __shared__ int tmp[1024];
    const int tid = threadIdx.x;
    const int h = hist[tid];
    tmp[tid] = h;
    __syncthreads();
    for (int off = 1; off < 1024; off <<= 1) {
        int v = (tid >= off) ? tmp[tid - off] : 0;
        __syncthreads();
        tmp[tid] += v;
        __syncthreads();
    }
    int ex = tmp[tid] - h;   // exclusive
    offs[tid] = ex;
    curs[tid] = ex;
}

// ---------------- K3: fill row-id bins ----------------
__global__ __launch_bounds__(256) void k_fill(
    const int* __restrict__ idx_in, int* __restrict__ curs, int* __restrict__ rowids)
{
    int r = blockIdx.x * 256 + threadIdx.x;
    int c = idx_in[r];
    int slot = atomicAdd(&curs[c], 1);
    rowids[slot] = r;
}

// ---------------- K4: per-code dw + quantized gather-write + loss (atomic-free) ----------------
__global__ __launch_bounds__(256) void k_dw(
    const float* __restrict__ x, const float* __restrict__ ew,
    const int* __restrict__ hist, const int* __restrict__ offs,
    const int* __restrict__ rowids,
    float* __restrict__ q_out, float* __restrict__ dw, double* __restrict__ lossp)
{
    const int c = blockIdx.x;
    const int tid = threadIdx.x;          // == d
    const int n = hist[c];
    const int base = offs[c];
    const float ev = ew[(size_t)c * 256 + tid];
    float acc = 0.f;
    float lsum = 0.f;
    for (int i = 0; i < n; ++i) {
        int row = rowids[base + i];
        float xv = x[(size_t)row * 256 + tid];
        q_out[(size_t)row * 256 + tid] = ev;
        acc += xv;
        float df = ev - xv;
        lsum += df * df;
    }
    dw[(size_t)c * 256 + tid] = acc;
    // block-reduce lsum
    const int lane = tid & 63, wid = tid >> 6;
    __shared__ float wsum[4];
#pragma unroll
    for (int m = 1; m < 64; m <<= 1) lsum += __shfl_xor(lsum, m);
    if (lane == 0) wsum[wid] = lsum;
    __syncthreads();
    if (tid == 0)
        lossp[c] = (double)wsum[0] + wsum[1] + wsum[2] + wsum[3];
}

// ---------------- K5: finalize new_cs (+ n) and loss ----------------
__global__ __launch_bounds__(1024) void k_finalize(
    const float* __restrict__ ema_cs, const int* __restrict__ hist,
    const double* __restrict__ lossp, float* __restrict__ out)
{
    __shared__ double red[1024];
    const int tid = threadIdx.x;
    float raw = ema_cs[tid] * 0.99f + 0.01f * (float)hist[tid];
    red[tid] = (double)raw;
    __syncthreads();
    for (int s = 512; s > 0; s >>= 1) {
        if (tid < s) red[tid] += red[tid + s];
        __syncthreads();
    }
    double n = red[0];
    __syncthreads();
    float csn = (raw + 1e-5f) * (float)(n / (n + 1024.0 * 1e-5));
    out[OFF_CS + tid] = csn;
    red[tid] = lossp[tid];
    __syncthreads();
    for (int s = 512; s > 0; s >>= 1) {
        if (tid < s) red[tid] += red[tid + s];
        __syncthreads();
    }
    if (tid == 0) out[OFF_LOSS] = (float)(red[0] * 1.25 / 16777216.0);
}

// ---------------- K6: new_ema_w + updated_embed ----------------
__global__ __launch_bounds__(256) void k_ema(
    const float* __restrict__ ema_w, const float* __restrict__ dw,
    const float* __restrict__ cs_out, float* __restrict__ out)
{
    int id = blockIdx.x * 256 + threadIdx.x;   // 0..262143
    int k = id >> 8;
    float nw = ema_w[id] * 0.99f + 0.01f * dw[id];
    out[OFF_EMAW + id] = nw;
    out[OFF_UPD + id] = nw / cs_out[k];
}

extern "C" void kernel_launch(void* const* d_in, const int* in_sizes, int n_in,
                              void* d_out, int out_size, void* d_ws, size_t ws_size,
                              hipStream_t stream)
{
    const float* x      = (const float*)d_in[0];
    const float* ew     = (const float*)d_in[1];
    const float* ema_cs = (const float*)d_in[2];
    const float* ema_w  = (const float*)d_in[3];
    float* out = (float*)d_out;
    char* ws = (char*)d_ws;

    int*    hist    = (int*)(ws + WS_HIST);
    int*    offs    = (int*)(ws + WS_OFFS);
    int*    curs    = (int*)(ws + WS_CURS);
    int*    idxi    = (int*)(ws + WS_IDX);
    int*    rowids  = (int*)(ws + WS_ROWIDS);
    float*  sqx     = (float*)(ws + WS_SQX);
    float*  sqe     = (float*)(ws + WS_SQE);
    float*  dw      = (float*)(ws + WS_DW);
    double* lossp   = (double*)(ws + WS_LOSSP);

    hipMemsetAsync(hist, 0, 4096, stream);
    hipLaunchKernelGGL(k_sq, dim3(NROWS / 256), dim3(256), 0, stream, x, sqx, NROWS);
    hipLaunchKernelGGL(k_sq, dim3(K / 256), dim3(256), 0, stream, ew, sqe, K);
    hipLaunchKernelGGL(k_argmin, dim3(NROWS / 64), dim3(256), 0, stream,
                       x, ew, sqx, sqe, idxi, out + OFF_IDX, hist);
    hipLaunchKernelGGL(k_prefix, dim3(1), dim3(1024), 0, stream, hist, offs, curs);
    hipLaunchKernelGGL(k_fill, dim3(NROWS / 256), dim3(256), 0, stream,
                       idxi, curs, rowids);
    hipLaunchKernelGGL(k_dw, dim3(K), dim3(256), 0, stream,
                       x, ew, hist, offs, rowids, out + OFF_Q, dw, lossp);
    hipLaunchKernelGGL(k_finalize, dim3(1), dim3(1024), 0, stream,
                       ema_cs, hist, lossp, out);
    hipLaunchKernelGGL(k_ema, dim3(1024), dim3(256), 0, stream,
                       ema_w, dw, out + OFF_CS, out);
}

// Round 6
// 526.150 us; speedup vs baseline: 2.8547x; 1.1531x over previous
//
#include <hip/hip_runtime.h>
#include <math.h>

#define NROWS 65536
#define D 256
#define K 1024

// d_out offsets (floats)
#define OFF_Q     0
#define OFF_LOSS  16777216
#define OFF_IDX   16777217
#define OFF_CS    16842753
#define OFF_EMAW  16843777
#define OFF_UPD   17105921

// ws offsets (bytes)
#define WS_HIST     0          // 1024 int  (memset)
#define WS_OFFS     4096       // 1024 int
#define WS_CURS     8192       // 1024 int
#define WS_IDX      12288      // 65536 int
#define WS_ROWIDS   274432     // 65536 int
#define WS_SQX      536576     // 65536 f32
#define WS_SQE      798720     // 1024 f32
#define WS_DW       802816     // 262144 f32
#define WS_LOSSP    1851392    // 1024 double (ends 1859584)

__device__ __forceinline__ void gload16(const void* g, void* l) {
    __builtin_amdgcn_global_load_lds(
        (const __attribute__((address_space(1))) void*)g,
        (__attribute__((address_space(3))) void*)l, 16, 0, 0);
}

// ---------------- K0: row sum-of-squares, numpy AVX512 pairwise order ----------------
__global__ __launch_bounds__(256) void k_sq(const float* __restrict__ a_,
                                            float* __restrict__ dst, int n)
{
#pragma clang fp contract(off)
    int r = blockIdx.x * 256 + threadIdx.x;
    if (r >= n) return;
    const float4* a4 = (const float4*)(a_ + (size_t)r * 256);
    float h[2];
#pragma unroll
    for (int hh = 0; hh < 2; ++hh) {
        float p[4][16];
#pragma unroll
        for (int pr = 0; pr < 4; ++pr) {      // pair (2pr, 2pr+1) of 16-float chunks
#pragma unroll
            for (int m = 0; m < 4; ++m) {
                float4 u = a4[hh * 32 + (2 * pr) * 4 + m];
                float4 v = a4[hh * 32 + (2 * pr + 1) * 4 + m];
                p[pr][4 * m + 0] = u.x * u.x + v.x * v.x;
                p[pr][4 * m + 1] = u.y * u.y + v.y * v.y;
                p[pr][4 * m + 2] = u.z * u.z + v.z * v.z;
                p[pr][4 * m + 3] = u.w * u.w + v.w * v.w;
            }
        }
        float V[16];
#pragma unroll
        for (int l = 0; l < 16; ++l) V[l] = (p[0][l] + p[1][l]) + (p[2][l] + p[3][l]);
        float t[8];
#pragma unroll
        for (int l = 0; l < 8; ++l) t[l] = V[l] + V[l + 8];
        float u2[4];
#pragma unroll
        for (int l = 0; l < 4; ++l) u2[l] = t[l] + t[l + 4];
        h[hh] = (u2[0] + u2[2]) + (u2[1] + u2[3]);
    }
    dst[r] = h[0] + h[1];
}

// ---------------- K1: tiled f32 GEMM-argmin, numpy/BLAS-exact arithmetic ----------------
// 128 rows x 1024 codes per block (4 ct-tiles of 256 codes); acc[8][16]/thread.
// Thread rows r = ty + 16i; thread codes c = ct*256 + 16j + tx.
// LDS natural row-major [r][32] with XOR swizzle: d-group g stored at g^(r&7).
// Staged via global_load_lds(16B) with pre-swizzled per-lane global source.
// Per (row,code): single f32 accumulator, fmaf over k ascending (BLAS order).
// dist = (sqx - 2*dot) + sqe  (two separate f32 roundings); argmin = lex-min(value, index).
__global__ __launch_bounds__(256, 2) void k_argmin(
    const float* __restrict__ x, const float* __restrict__ ew,
    const float* __restrict__ sqx, const float* __restrict__ sqe,
    int* __restrict__ idx_out, float* __restrict__ idxf_out,
    int* __restrict__ hist)
{
#pragma clang fp contract(off)
    __shared__ __align__(16) float xs[128][32];   // 16 KB
    __shared__ __align__(16) float es[256][32];   // 32 KB
    const int tid = threadIdx.x;
    const int w = tid >> 6, l = tid & 63;
    const int tx = tid & 15, ty = tid >> 4;
    const int row0 = blockIdx.x * 128;
    const int lr = l >> 3;      // sub-row within a 1KB issue
    const int lg = l & 7;       // stored 16B-group within row

    float sxv[8];
#pragma unroll
    for (int i = 0; i < 8; ++i) sxv[i] = sqx[row0 + ty + 16 * i];

    float best1[8]; int bidx[8];
#pragma unroll
    for (int i = 0; i < 8; ++i) { best1[i] = 3.4e38f; bidx[i] = 0x7fffffff; }

#pragma unroll 1
    for (int ct = 0; ct < 4; ++ct) {
        float acc[8][16];
#pragma unroll
        for (int i = 0; i < 8; ++i)
#pragma unroll
            for (int j = 0; j < 16; ++j) acc[i][j] = 0.f;

#pragma unroll 1
        for (int dc = 0; dc < 8; ++dc) {
            __syncthreads();
            // stage x tile: 128 rows x 32 d = 16KB, 16 issues (4/wave)
#pragma unroll
            for (int q4 = 0; q4 < 4; ++q4) {
                const int q = w + 4 * q4;
                const int r = q * 8 + lr;
                const int g = lg ^ (r & 7);
                gload16(&x[(size_t)(row0 + r) * 256 + dc * 32 + 4 * g], &xs[q * 8][0]);
            }
            // stage e tile: 256 codes x 32 d = 32KB, 32 issues (8/wave)
#pragma unroll
            for (int q8 = 0; q8 < 8; ++q8) {
                const int q = w + 4 * q8;
                const int c = q * 8 + lr;
                const int g = lg ^ (c & 7);
                gload16(&ew[(size_t)(ct * 256 + c) * 256 + dc * 32 + 4 * g], &es[q * 8][0]);
            }
            __syncthreads();
#pragma unroll 1
            for (int dq = 0; dq < 8; ++dq) {
                float4 xa[8];
#pragma unroll
                for (int i = 0; i < 8; ++i) {
                    const int r = ty + 16 * i;
                    xa[i] = *(const float4*)&xs[r][4 * (dq ^ (r & 7))];
                }
#pragma unroll
                for (int j = 0; j < 16; ++j) {
                    const int c = 16 * j + tx;
                    const float4 ev = *(const float4*)&es[c][4 * (dq ^ (c & 7))];
#pragma unroll
                    for (int i = 0; i < 8; ++i) {
                        acc[i][j] = __builtin_fmaf(xa[i].x, ev.x, acc[i][j]);
                        acc[i][j] = __builtin_fmaf(xa[i].y, ev.y, acc[i][j]);
                        acc[i][j] = __builtin_fmaf(xa[i].z, ev.z, acc[i][j]);
                        acc[i][j] = __builtin_fmaf(xa[i].w, ev.w, acc[i][j]);
                    }
                }
            }
        }
        // epilogue for this ct: distances + lex-min
#pragma unroll
        for (int i = 0; i < 8; ++i) {
            float v1 = 3.4e38f; int i1 = 0x7fffffff;
#pragma unroll
            for (int j = 0; j < 16; ++j) {
                const int c = ct * 256 + 16 * j + tx;
                float t = sxv[i] - 2.0f * acc[i][j];   // one rounding (2*acc exact)
                float s = t + sqe[c];                  // second rounding (numpy order)
                if (s < v1 || (s == v1 && c < i1)) { v1 = s; i1 = c; }
            }
#pragma unroll
            for (int m = 1; m < 16; m <<= 1) {
                float o1 = __shfl_xor(v1, m);
                int    oi = __shfl_xor(i1, m);
                if (o1 < v1 || (o1 == v1 && oi < i1)) { v1 = o1; i1 = oi; }
            }
            if (v1 < best1[i] || (v1 == best1[i] && i1 < bidx[i])) {
                best1[i] = v1; bidx[i] = i1;
            }
        }
    }
    if (tx == 0) {
#pragma unroll
        for (int i = 0; i < 8; ++i) {
            const int row = row0 + ty + 16 * i;
            idx_out[row] = bidx[i];
            idxf_out[row] = (float)bidx[i];
            atomicAdd(&hist[bidx[i]], 1);
        }
    }
}

// ---------------- K2: prefix sum of histogram -> offsets + cursors ----------------
__global__ __launch_bounds__(1024) void k_prefix(
    const int* __restrict__ hist, int* __restrict__ offs, int* __restrict__ curs)
{
    __shared__ int tmp[1024];
    const int tid = threadIdx.x;
    const int h = hist[tid];
    tmp[tid] = h;
    __syncthreads();
    for (int off = 1; off < 1024; off <<= 1) {
        int v = (tid >= off) ? tmp[tid - off] : 0;
        __syncthreads();
        tmp[tid] += v;
        __syncthreads();
    }
    int ex = tmp[tid] - h;   // exclusive
    offs[tid] = ex;
    curs[tid] = ex;
}

// ---------------- K3: fill row-id bins ----------------
__global__ __launch_bounds__(256) void k_fill(
    const int* __restrict__ idx_in, int* __restrict__ curs, int* __restrict__ rowids)
{
    int r = blockIdx.x * 256 + threadIdx.x;
    int c = idx_in[r];
    int slot = atomicAdd(&curs[c], 1);
    rowids[slot] = r;
}

// ---------------- K4: per-code dw + quantized gather-write + loss (atomic-free) ----------------
__global__ __launch_bounds__(256) void k_dw(
    const float* __restrict__ x, const float* __restrict__ ew,
    const int* __restrict__ hist, const int* __restrict__ offs,
    const int* __restrict__ rowids,
    float* __restrict__ q_out, float* __restrict__ dw, double* __restrict__ lossp)
{
    const int c = blockIdx.x;
    const int tid = threadIdx.x;          // == d
    const int n = hist[c];
    const int base = offs[c];
    const float ev = ew[(size_t)c * 256 + tid];
    float acc = 0.f;
    float lsum = 0.f;
    for (int i = 0; i < n; ++i) {
        int row = rowids[base + i];
        float xv = x[(size_t)row * 256 + tid];
        q_out[(size_t)row * 256 + tid] = ev;
        acc += xv;
        float df = ev - xv;
        lsum += df * df;
    }
    dw[(size_t)c * 256 + tid] = acc;
    const int lane = tid & 63, wid = tid >> 6;
    __shared__ float wsum[4];
#pragma unroll
    for (int m = 1; m < 64; m <<= 1) lsum += __shfl_xor(lsum, m);
    if (lane == 0) wsum[wid] = lsum;
    __syncthreads();
    if (tid == 0)
        lossp[c] = (double)wsum[0] + wsum[1] + wsum[2] + wsum[3];
}

// ---------------- K5: finalize new_cs (+ n) and loss ----------------
__global__ __launch_bounds__(1024) void k_finalize(
    const float* __restrict__ ema_cs, const int* __restrict__ hist,
    const double* __restrict__ lossp, float* __restrict__ out)
{
    __shared__ double red[1024];
    const int tid = threadIdx.x;
    float raw = ema_cs[tid] * 0.99f + 0.01f * (float)hist[tid];
    red[tid] = (double)raw;
    __syncthreads();
    for (int s = 512; s > 0; s >>= 1) {
        if (tid < s) red[tid] += red[tid + s];
        __syncthreads();
    }
    double n = red[0];
    __syncthreads();
    float csn = (raw + 1e-5f) * (float)(n / (n + 1024.0 * 1e-5));
    out[OFF_CS + tid] = csn;
    red[tid] = lossp[tid];
    __syncthreads();
    for (int s = 512; s > 0; s >>= 1) {
        if (tid < s) red[tid] += red[tid + s];
        __syncthreads();
    }
    if (tid == 0) out[OFF_LOSS] = (float)(red[0] * 1.25 / 16777216.0);
}

// ---------------- K6: new_ema_w + updated_embed ----------------
__global__ __launch_bounds__(256) void k_ema(
    const float* __restrict__ ema_w, const float* __restrict__ dw,
    const float* __restrict__ cs_out, float* __restrict__ out)
{
    int id = blockIdx.x * 256 + threadIdx.x;   // 0..262143
    int k = id >> 8;
    float nw = ema_w[id] * 0.99f + 0.01f * dw[id];
    out[OFF_EMAW + id] = nw;
    out[OFF_UPD + id] = nw / cs_out[k];
}

extern "C" void kernel_launch(void* const* d_in, const int* in_sizes, int n_in,
                              void* d_out, int out_size, void* d_ws, size_t ws_size,
                              hipStream_t stream)
{
    const float* x      = (const float*)d_in[0];
    const float* ew     = (const float*)d_in[1];
    const float* ema_cs = (const float*)d_in[2];
    const float* ema_w  = (const float*)d_in[3];
    float* out = (float*)d_out;
    char* ws = (char*)d_ws;

    int*    hist    = (int*)(ws + WS_HIST);
    int*    offs    = (int*)(ws + WS_OFFS);
    int*    curs    = (int*)(ws + WS_CURS);
    int*    idxi    = (int*)(ws + WS_IDX);
    int*    rowids  = (int*)(ws + WS_ROWIDS);
    float*  sqx     = (float*)(ws + WS_SQX);
    float*  sqe     = (float*)(ws + WS_SQE);
    float*  dw      = (float*)(ws + WS_DW);
    double* lossp   = (double*)(ws + WS_LOSSP);

    hipMemsetAsync(hist, 0, 4096, stream);
    hipLaunchKernelGGL(k_sq, dim3(NROWS / 256), dim3(256), 0, stream, x, sqx, NROWS);
    hipLaunchKernelGGL(k_sq, dim3(K / 256), dim3(256), 0, stream, ew, sqe, K);
    hipLaunchKernelGGL(k_argmin, dim3(NROWS / 128), dim3(256), 0, stream,
                       x, ew, sqx, sqe, idxi, out + OFF_IDX, hist);
    hipLaunchKernelGGL(k_prefix, dim3(1), dim3(1024), 0, stream, hist, offs, curs);
    hipLaunchKernelGGL(k_fill, dim3(NROWS / 256), dim3(256), 0, stream,
                       idxi, curs, rowids);
    hipLaunchKernelGGL(k_dw, dim3(K), dim3(256), 0, stream,
                       x, ew, hist, offs, rowids, out + OFF_Q, dw, lossp);
    hipLaunchKernelGGL(k_finalize, dim3(1), dim3(1024), 0, stream,
                       ema_cs, hist, lossp, out);
    hipLaunchKernelGGL(k_ema, dim3(1024), dim3(256), 0, stream,
                       ema_w, dw, out + OFF_CS, out);
}